// Round 2
// baseline (286.099 us; speedup 1.0000x reference)
//
#include <hip/hip_runtime.h>
#include <hip/hip_bf16.h>

// Problem constants (from reference setup_inputs): B=2, Np=Nc=512, D=P=128.
#define BATCH 2
#define NP 512
#define NC 512
#define DD 128
#define PP 128

typedef __bf16 bf16_t;
typedef __bf16 bf16x8 __attribute__((ext_vector_type(8)));
typedef float f32x4 __attribute__((ext_vector_type(4)));

// ---------------- Stage 1: layernorm rows (one wave per row of 128) --------
__global__ __launch_bounds__(64) void ln_kernel(const float* __restrict__ x,
                                                const float* __restrict__ w,
                                                const float* __restrict__ bsh,
                                                float* __restrict__ y) {
    int row = blockIdx.x;
    int t = threadIdx.x;              // 0..63, each handles 2 contiguous elems
    const float* xr = x + (size_t)row * DD;
    float2 v = *(const float2*)&xr[2 * t];
    float s  = v.x + v.y;
    float sq = v.x * v.x + v.y * v.y;
    // butterfly reduce across the 64-lane wave
    for (int o = 32; o; o >>= 1) {
        s  += __shfl_xor(s, o);
        sq += __shfl_xor(sq, o);
    }
    float mu  = s * (1.0f / 128.0f);
    float var = sq * (1.0f / 128.0f) - mu * mu;
    float rs  = rsqrtf(var + 1e-5f);
    float2 wv = *(const float2*)&w[2 * t];
    float2 bv = *(const float2*)&bsh[2 * t];
    float* yr = y + (size_t)row * DD;
    float2 o2;
    o2.x = (v.x - mu) * rs * wv.x + bv.x;
    o2.y = (v.y - mu) * rs * wv.y + bv.y;
    *(float2*)&yr[2 * t] = o2;
}

// ---------------- Stage 2: W fp32 -> bf16 ----------------------------------
__global__ __launch_bounds__(256) void cvt_kernel(const float* __restrict__ W,
                                                  bf16_t* __restrict__ Wb) {
    int idx = blockIdx.x * 256 + threadIdx.x;
    Wb[idx] = (bf16_t)W[idx];
}

// ---------------- Stage 3: main fused interaction kernel -------------------
// One block per (b, i, j-tile of 128). Computes out[b,i,j0:j0+128, 0:128]
// = (c_ln[j,:] * p_ln[i,:]) @ W^T + b_out, masked. 4 waves, each a 64x64
// sub-tile via 4x4 grid of 16x16x32 bf16 MFMAs over K=128.
__global__ __launch_bounds__(256) void inter_kernel(
    const float* __restrict__ p_ln, const float* __restrict__ c_ln,
    const bf16_t* __restrict__ Wb, const float* __restrict__ b_out,
    const int* __restrict__ p_mask,      // bool inputs marshaled as int32
    const int* __restrict__ c_mask,
    float* __restrict__ out) {
    // +8 bf16 pad (16 B) per row: keeps 16B alignment, staggers banks
    __shared__ bf16_t As[128][136];
    __shared__ bf16_t Ws[128][136];

    int blk = blockIdx.x;            // 4096 blocks
    int jt = blk & 3;                // 4 j-tiles
    int i  = (blk >> 2) & 511;
    int b  = blk >> 11;
    int j0 = jt * 128;

    int t = threadIdx.x;             // 256 threads
    int kcol = (t & 15) * 8;         // k-column this thread stages (8 elems)
    int rgrp = t >> 4;               // 16 rows per pass

    // p row for this block's i (fp32, reused across all 8 staging passes)
    const float* prow = p_ln + ((size_t)(b * NP + i)) * DD + kcol;
    float4 p0 = *(const float4*)&prow[0];
    float4 p1 = *(const float4*)&prow[4];

    const float* cbase = c_ln + ((size_t)(b * NC + j0)) * DD;
    #pragma unroll
    for (int pass = 0; pass < 8; ++pass) {
        int row = pass * 16 + rgrp;
        const float* cr = cbase + (size_t)row * DD + kcol;
        float4 c0 = *(const float4*)&cr[0];
        float4 c1 = *(const float4*)&cr[4];
        bf16x8 av;
        av[0] = (bf16_t)(c0.x * p0.x); av[1] = (bf16_t)(c0.y * p0.y);
        av[2] = (bf16_t)(c0.z * p0.z); av[3] = (bf16_t)(c0.w * p0.w);
        av[4] = (bf16_t)(c1.x * p1.x); av[5] = (bf16_t)(c1.y * p1.y);
        av[6] = (bf16_t)(c1.z * p1.z); av[7] = (bf16_t)(c1.w * p1.w);
        *(bf16x8*)&As[row][kcol] = av;
        // stage W tile (already bf16) alongside
        const bf16_t* wr = Wb + (size_t)row * DD + kcol;
        *(bf16x8*)&Ws[row][kcol] = *(const bf16x8*)wr;
    }
    __syncthreads();

    int lane = t & 63;
    int wave = t >> 6;
    int wm = wave >> 1, wn = wave & 1;   // 2x2 wave grid over 128x128
    int m0 = wm * 64, n0 = wn * 64;
    int l16 = lane & 15, q = lane >> 4;

    f32x4 acc[4][4];
    #pragma unroll
    for (int mi = 0; mi < 4; ++mi)
        #pragma unroll
        for (int ni = 0; ni < 4; ++ni)
            acc[mi][ni] = (f32x4){0.f, 0.f, 0.f, 0.f};

    #pragma unroll
    for (int kk = 0; kk < 4; ++kk) {
        int kb = kk * 32 + q * 8;
        bf16x8 a[4], w[4];
        #pragma unroll
        for (int mi = 0; mi < 4; ++mi)
            a[mi] = *(const bf16x8*)&As[m0 + mi * 16 + l16][kb];
        #pragma unroll
        for (int ni = 0; ni < 4; ++ni)
            w[ni] = *(const bf16x8*)&Ws[n0 + ni * 16 + l16][kb];
        #pragma unroll
        for (int mi = 0; mi < 4; ++mi)
            #pragma unroll
            for (int ni = 0; ni < 4; ++ni)
                acc[mi][ni] = __builtin_amdgcn_mfma_f32_16x16x32_bf16(
                    a[mi], w[ni], acc[mi][ni], 0, 0, 0);
    }

    // ---------------- epilogue: bias + mask + store ----------------
    int pm = p_mask[b * NP + i];
    float bias[4];
    #pragma unroll
    for (int ni = 0; ni < 4; ++ni)
        bias[ni] = b_out[n0 + ni * 16 + l16];

    size_t outbase = (((size_t)b * NP + i) * NC) * PP;
    #pragma unroll
    for (int mi = 0; mi < 4; ++mi) {
        #pragma unroll
        for (int reg = 0; reg < 4; ++reg) {
            int j = j0 + m0 + mi * 16 + q * 4 + reg;  // C/D row = q*4+reg
            int cm = c_mask[b * NC + j];
            float scale = (pm != 0 && cm != 0) ? 1.0f : 0.0f;
            float* orow = out + outbase + (size_t)j * PP;
            #pragma unroll
            for (int ni = 0; ni < 4; ++ni)            // C/D col = l16
                orow[n0 + ni * 16 + l16] = (acc[mi][ni][reg] + bias[ni]) * scale;
        }
    }

    // mask output chunk for this (b,i,j-tile): 128 floats, written once
    if (t < 128) {
        int j = j0 + t;
        int cm = c_mask[b * NC + j];
        size_t mbase = (size_t)BATCH * NP * NC * PP;
        out[mbase + ((size_t)b * NP + i) * NC + j] =
            (pm != 0 && cm != 0) ? 1.0f : 0.0f;
    }
}

extern "C" void kernel_launch(void* const* d_in, const int* in_sizes, int n_in,
                              void* d_out, int out_size, void* d_ws, size_t ws_size,
                              hipStream_t stream) {
    const float* p_embed = (const float*)d_in[0];
    const float* c_embed = (const float*)d_in[1];
    const int* p_mask = (const int*)d_in[2];   // bool -> int32 per harness rule
    const int* c_mask = (const int*)d_in[3];
    const float* ln_p_w = (const float*)d_in[4];
    const float* ln_p_b = (const float*)d_in[5];
    const float* ln_c_w = (const float*)d_in[6];
    const float* ln_c_b = (const float*)d_in[7];
    const float* W_out  = (const float*)d_in[8];
    const float* b_out  = (const float*)d_in[9];
    float* out = (float*)d_out;

    // workspace layout: p_ln f32 [2*512*128] | c_ln f32 [2*512*128] | W bf16 [128*128]
    float* p_ln = (float*)d_ws;
    float* c_ln = p_ln + (size_t)BATCH * NP * DD;
    bf16_t* w_bf = (bf16_t*)(c_ln + (size_t)BATCH * NC * DD);

    ln_kernel<<<BATCH * NP, 64, 0, stream>>>(p_embed, ln_p_w, ln_p_b, p_ln);
    ln_kernel<<<BATCH * NC, 64, 0, stream>>>(c_embed, ln_c_w, ln_c_b, c_ln);
    cvt_kernel<<<(PP * DD) / 256, 256, 0, stream>>>(W_out, w_bf);
    inter_kernel<<<BATCH * NP * (NC / 128), 256, 0, stream>>>(
        p_ln, c_ln, w_bf, b_out, p_mask, c_mask, out);
}